// Round 14
// baseline (434.667 us; speedup 1.0000x reference)
//
#include <hip/hip_runtime.h>
#include <hip/hip_bf16.h>
#include <stdint.h>

#define NN 100000
#define NE 1600000
#define FIN 100
#define HID 128
#define CLS 47
#define NBUK 391            // ceil(NN/256) buckets of 256 nodes
#define BCAP 4992           // fixed bucket capacity: mean 4096 + 8 sigma + even-pad (<=256) + 16

typedef __attribute__((ext_vector_type(8))) short bf16x8;
typedef __attribute__((ext_vector_type(4))) float f32x4;
typedef __attribute__((ext_vector_type(2))) float f32x2;

#define AS1(p) ((const __attribute__((address_space(1))) void*)(p))
#define AS3(p) ((__attribute__((address_space(3))) void*)(p))

__device__ __forceinline__ uint16_t f2bf(float f) {
  union { float f; uint32_t u; } v; v.f = f;
  uint32_t r = v.u + 0x7fffu + ((v.u >> 16) & 1u);
  return (uint16_t)(r >> 16);
}

// ---- weight packing: B_l[j][k] (128 x 256) bf16; k<128 -> W_rel, k>=128 -> W_root (layer1 zero-padded)
__global__ void pack_weights(const float* __restrict__ W1r, const float* __restrict__ W1o,
                             const float* __restrict__ W2r, const float* __restrict__ W2o,
                             const float* __restrict__ W3r, const float* __restrict__ W3o,
                             uint16_t* __restrict__ B1, uint16_t* __restrict__ B2, uint16_t* __restrict__ B3) {
  int idx = blockIdx.x * 256 + threadIdx.x;      // < 3*128*256
  int l = idx >> 15;
  int rem = idx & 32767;
  int j = rem >> 8;
  int k = rem & 255;
  if (l == 0) {
    uint16_t v = 0;
    if (k < FIN) v = f2bf(W1r[j*FIN + k]);
    else if (k >= 128 && k < 128 + FIN) v = f2bf(W1o[j*FIN + (k - 128)]);
    B1[j*256 + k] = v;
  } else if (l == 1) {
    B2[j*256 + k] = (k < 128) ? f2bf(W2r[j*128 + k]) : f2bf(W2o[j*128 + (k - 128)]);
  } else {
    B3[j*256 + k] = (k < 128) ? f2bf(W3r[j*128 + k]) : f2bf(W3o[j*128 + (k - 128)]);
  }
}

// ---- W_lin [47,384] f32 -> Wlb [48,384] bf16 (row 47 zero)
__global__ void pack_wl(const float* __restrict__ Wl, uint16_t* __restrict__ Wlb) {
  int idx = blockIdx.x * 256 + threadIdx.x;      // < 48*384
  int r = idx / 384;
  int c = idx - r * 384;
  Wlb[idx] = (r < CLS) ? f2bf(Wl[r*384 + c]) : (uint16_t)0;
}

// ---- pad+convert x0 [N,100] f32 -> x0p [N,128] bf16 AND x0f8 [N,128] fp8 (zeros past col 99)
__global__ __launch_bounds__(256) void pad_x0(const float* __restrict__ x0, uint16_t* __restrict__ x0p,
                                              uint8_t* __restrict__ x0f8) {
  int n = blockIdx.x * 4 + (threadIdx.x >> 6);
  int c = 2 * (threadIdx.x & 63);
  uint32_t o = 0;
  uint16_t o8 = 0;
  if (c < FIN) {
    float2 v = *(const float2*)(x0 + (size_t)n*FIN + c);
    o = ((uint32_t)f2bf(v.y) << 16) | (uint32_t)f2bf(v.x);
    o8 = (uint16_t)__builtin_amdgcn_cvt_pk_fp8_f32(v.x, v.y, 0, false);
  }
  *(uint32_t*)(x0p + (size_t)n*HID + c) = o;
  *(uint16_t*)(x0f8 + (size_t)n*128 + c) = o8;
}

// ======== binned CSR build (fixed-capacity buckets) ========
// Stage 0: bfill[b] = b*BCAP
__global__ void binit(int* __restrict__ bfill) {
  int i = blockIdx.x * 256 + threadIdx.x;
  if (i < NBUK) bfill[i] = i * BCAP;
}

// Stage 1: binned scatter. Each block claims contiguous per-bucket chunks so all
// writes to a chunk come from ONE CU -> L2 write-combining -> full-line writebacks.
// Packed rec: x = src | dstLocal<<17 (src<2^17, dstLocal<256), y = weight bits.
__global__ __launch_bounds__(512) void binscat(const int* __restrict__ src, const int* __restrict__ dst,
                                               const float* __restrict__ ew,
                                               int* __restrict__ bfill, int2* __restrict__ ebin) {
  __shared__ int h[NBUK];
  __shared__ int base[NBUK];
  int tid = threadIdx.x;
  for (int i = tid; i < NBUK; i += 512) h[i] = 0;
  __syncthreads();
  int tile0 = blockIdx.x * 8192;
  int n = NE - tile0; if (n > 8192) n = 8192;
  for (int i = tid; i < n; i += 512) atomicAdd(&h[dst[tile0 + i] >> 8], 1);
  __syncthreads();
  for (int i = tid; i < NBUK; i += 512) base[i] = h[i] ? atomicAdd(&bfill[i], h[i]) : 0;
  __syncthreads();
  for (int i = tid; i < NBUK; i += 512) h[i] = 0;
  __syncthreads();
  for (int i = tid; i < n; i += 512) {
    int e = tile0 + i;
    int d = dst[e];
    int b = d >> 8;
    int r = atomicAdd(&h[b], 1);
    ebin[base[b] + r] = make_int2(src[e] | ((d & 255) << 17), __float_as_int(ew[e]));
  }
}

// Stage 2: one block per bucket. LDS hist+scan (even-rounded per-node counts so
// every row stream starts 16B-aligned for int4 erec loads) -> row_desc{start,deg},
// then scatter erec {src byte-offset, weight}. Odd-degree gap slots and 16
// bucket-end slots are zeroed so overrunning tail reads see valid offsets.
__global__ __launch_bounds__(256) void bucket_csr(const int2* __restrict__ ebin,
                                                  const int* __restrict__ bfill,
                                                  int2* __restrict__ row_desc,
                                                  int2* __restrict__ erec) {
  __shared__ int sh[256];
  __shared__ int fill[256];
  __shared__ int cnt2s;
  int b = blockIdx.x;
  int tid = threadIdx.x;
  int base = b * BCAP;
  int cnt = bfill[b] - base;
  sh[tid] = 0;
  __syncthreads();
  for (int i = tid; i < cnt; i += 256) atomicAdd(&sh[(uint32_t)ebin[base + i].x >> 17], 1);
  __syncthreads();
  int histv = sh[tid];
  int hist2 = (histv + 1) & ~1;            // even-rounded
  __syncthreads();
  sh[tid] = hist2;
  __syncthreads();
  for (int off = 1; off < 256; off <<= 1) {
    int tv = (tid >= off) ? sh[tid - off] : 0;
    __syncthreads();
    sh[tid] += tv;
    __syncthreads();
  }
  int excl2 = sh[tid] - hist2;             // even
  if (tid == 255) cnt2s = sh[255];
  int node = b * 256 + tid;
  if (node < NN) row_desc[node] = make_int2(base + excl2, histv);
  fill[tid] = base + excl2;
  if (histv & 1) erec[base + excl2 + histv] = make_int2(0, 0);  // gap slot
  __syncthreads();
  for (int i = tid; i < cnt; i += 256) {
    int2 rec = ebin[base + i];
    int dl = (uint32_t)rec.x >> 17;
    int s = rec.x & 0x1FFFF;
    int pos = atomicAdd(&fill[dl], 1);
    erec[pos] = make_int2(s << 7, rec.y);           // s*128 = byte offset into fp8 row
  }
  if (tid < 16) {
    int p = cnt2s + tid;
    if (p < BCAP) erec[base + p] = make_int2(0, 0);
  }
}

// ---- FUSED SpMM+GEMM: for each 64-row tile, phase 1 computes agg rows into a
// chunk-XOR-swizzled LDS tile (spmm inner loop identical to the proven R11/R13
// structure: half-wave per row, int4 erec, batches of 16, fp8 one-line gathers),
// phase 2 runs the R13 gemm with A(K<128) read from LDS (kills the agg HBM
// round-trip: 51MB/layer) and A(K>=128)/B staged via global_load_lds as before.
__global__ __launch_bounds__(256) void spmm_gemm_kernel(
    const uint8_t* __restrict__ x8,       // gather source: fp8 rows [NN][128]
    const int2* __restrict__ row_desc,
    const int2* __restrict__ erec,
    const uint16_t* __restrict__ Xr,      // root input bf16 [NN][128] (A2)
    const uint16_t* __restrict__ Bm,      // weights [128][256]
    const float* __restrict__ bias,
    uint16_t* __restrict__ out, uint8_t* __restrict__ out8) {
  __shared__ uint16_t ldsAgg[64 * 128];   // 16KB; row r stores chunk ci at ci^(r&15)
  __shared__ uint16_t ldsA[64 * 32];      // 4KB, per-kt staging (rotation swizzle)
  __shared__ uint16_t ldsB[128 * 32];     // 8KB
  int t = threadIdx.x;
  int n0 = blockIdx.x * 64;
  int lane = t & 63, wave = t >> 6;
  int half = lane >> 5, li = lane & 31;

  // ---- phase 1: spmm for rows [n0, n0+64); wave w handles rows w*16..w*16+15
  const char* xb = (const char*)x8;
  int loff = 4 * li;
  for (int it = 0; it < 8; ++it) {
    int rloc = wave * 16 + 2 * it + half;          // 0..63
    int n = n0 + rloc;
    int s0 = 0, deg = 0;
    if (n < NN) { int2 rd = row_desc[n]; s0 = rd.x; deg = rd.y; }
    f32x2 a01 = (f32x2){0.f, 0.f}, a23 = (f32x2){0.f, 0.f};
    const int4* ep4 = (const int4*)(erec + s0);    // s0 even -> 16B aligned
    int nfull = deg & ~15;
    const int4* epf = ep4 + (nfull >> 1);
    for (; ep4 < epf; ep4 += 8) {
      int4 r[8];
      #pragma unroll
      for (int u = 0; u < 8; ++u) r[u] = ep4[u];
      uint32_t g[16];
      #pragma unroll
      for (int u = 0; u < 8; ++u) {
        g[2*u]   = *(const uint32_t*)(xb + (size_t)(uint32_t)(r[u].x + loff));
        g[2*u+1] = *(const uint32_t*)(xb + (size_t)(uint32_t)(r[u].z + loff));
      }
      __builtin_amdgcn_sched_barrier(0);
      #pragma unroll
      for (int u = 0; u < 8; ++u) {
        float w0 = __int_as_float(r[u].y);
        float w1 = __int_as_float(r[u].w);
        f32x2 w20 = (f32x2){w0, w0}, w21 = (f32x2){w1, w1};
        a01 += w20 * __builtin_amdgcn_cvt_pk_f32_fp8(g[2*u], false);
        a23 += w20 * __builtin_amdgcn_cvt_pk_f32_fp8(g[2*u], true);
        a01 += w21 * __builtin_amdgcn_cvt_pk_f32_fp8(g[2*u+1], false);
        a23 += w21 * __builtin_amdgcn_cvt_pk_f32_fp8(g[2*u+1], true);
      }
    }
    int rem = deg - nfull;
    if (rem) {                                     // tail: overrun records valid-or-zero; weights masked
      int4 r[8];
      #pragma unroll
      for (int u = 0; u < 8; ++u) r[u] = ep4[u];
      uint32_t g[16];
      #pragma unroll
      for (int u = 0; u < 8; ++u) {
        g[2*u]   = *(const uint32_t*)(xb + (size_t)(uint32_t)(r[u].x + loff));
        g[2*u+1] = *(const uint32_t*)(xb + (size_t)(uint32_t)(r[u].z + loff));
      }
      __builtin_amdgcn_sched_barrier(0);
      #pragma unroll
      for (int u = 0; u < 8; ++u) {
        float w0 = (2*u     < rem) ? __int_as_float(r[u].y) : 0.f;
        float w1 = (2*u + 1 < rem) ? __int_as_float(r[u].w) : 0.f;
        f32x2 w20 = (f32x2){w0, w0}, w21 = (f32x2){w1, w1};
        a01 += w20 * __builtin_amdgcn_cvt_pk_f32_fp8(g[2*u], false);
        a23 += w20 * __builtin_amdgcn_cvt_pk_f32_fp8(g[2*u], true);
        a01 += w21 * __builtin_amdgcn_cvt_pk_f32_fp8(g[2*u+1], false);
        a23 += w21 * __builtin_amdgcn_cvt_pk_f32_fp8(g[2*u+1], true);
      }
    }
    uint2 o;
    o.x = ((uint32_t)f2bf(a01[1]) << 16) | (uint32_t)f2bf(a01[0]);
    o.y = ((uint32_t)f2bf(a23[1]) << 16) | (uint32_t)f2bf(a23[0]);
    int ci = li >> 1;                              // 16B chunk 0..15 (cols 8*ci..8*ci+7)
    int cs = ci ^ (rloc & 15);
    *(uint2*)&ldsAgg[rloc * 128 + cs * 8 + (li & 1) * 4] = o;
  }
  __syncthreads();

  // ---- phase 2: gemm (R13 structure)
  int wm = (wave >> 1) * 32;            // 0 or 32
  int wn = (wave & 1) * 64;             // 0 or 64
  int l15 = lane & 15, quad = lane >> 4;

  f32x4 acc[2][4];
  #pragma unroll
  for (int i = 0; i < 2; ++i)
    #pragma unroll
    for (int j = 0; j < 4; ++j) acc[i][j] = (f32x4){0.f, 0.f, 0.f, 0.f};

  int ra = t >> 2, qa = t & 3;                     // A staging: row 0..63, dest chunk
  int qsA = (qa + (ra >> 1)) & 3;                  // source chunk (rotation)
  int rowA = n0 + ra; if (rowA >= NN) rowA = NN - 1;

  for (int kt = 0; kt < 8; ++kt) {
    int kbase = kt * 32;
    if (kt >= 4)
      __builtin_amdgcn_global_load_lds(AS1(Xr + (size_t)rowA*HID + (kbase - 128) + qsA*8), AS3(&ldsA[t * 8]), 16, 0, 0);
    #pragma unroll
    for (int p = 0; p < 2; ++p) {
      int u = t + p * 256;                         // 0..511
      int j = u >> 2, qb = u & 3;
      int qsB = (qb + (j >> 1)) & 3;
      __builtin_amdgcn_global_load_lds(AS1(Bm + j*256 + kbase + qsB*8), AS3(&ldsB[u * 8]), 16, 0, 0);
    }
    __syncthreads();
    bf16x8 af[2], bfr[4];
    #pragma unroll
    for (int mi = 0; mi < 2; ++mi) {
      int rA = wm + mi*16 + l15;
      if (kt < 4) {
        int ci = kt * 4 + quad;                    // chunk 0..15
        af[mi] = *(const bf16x8*)&ldsAgg[rA * 128 + (ci ^ (rA & 15)) * 8];
      } else {
        af[mi] = *(const bf16x8*)&ldsA[rA * 32 + ((quad - (rA >> 1)) & 3) * 8];
      }
    }
    #pragma unroll
    for (int ni = 0; ni < 4; ++ni) {
      int j = wn + ni*16 + l15;
      bfr[ni] = *(const bf16x8*)&ldsB[j * 32 + ((quad - (j >> 1)) & 3) * 8];
    }
    #pragma unroll
    for (int mi = 0; mi < 2; ++mi)
      #pragma unroll
      for (int ni = 0; ni < 4; ++ni)
        acc[mi][ni] = __builtin_amdgcn_mfma_f32_16x16x32_bf16(af[mi], bfr[ni], acc[mi][ni], 0, 0, 0);
    __syncthreads();
  }

  #pragma unroll
  for (int mi = 0; mi < 2; ++mi) {
    #pragma unroll
    for (int ni = 0; ni < 4; ++ni) {
      int c = wn + ni*16 + l15;
      float bc = bias[c];
      #pragma unroll
      for (int i = 0; i < 4; ++i) {
        int r = n0 + wm + mi*16 + quad*4 + i;
        if (r < NN) {
          float v = acc[mi][ni][i] + bc;
          v = v > 0.f ? v : 0.f;
          out[(size_t)r*HID + c] = f2bf(v);
          if (out8) out8[(size_t)r*128 + c] = (uint8_t)__builtin_amdgcn_cvt_pk_fp8_f32(v, v, 0, false);
        }
      }
    }
  }
}

// ---- final: logits = [x1|x2|x3] @ Wlb^T + bl ; log_softmax ; store f32
// 3 rounds (one per layer input): stage full 64x128 A-slice + 64x128 W-slice with
// row-contiguous global loads into XOR-swizzled LDS [row][c^(row&15)][8];
// conflict-free ds_read_b128 (bank = 4*(c^l15), disjoint). 6 barriers total.
__global__ __launch_bounds__(256) void final_kernel(const uint16_t* __restrict__ x1, const uint16_t* __restrict__ x2,
                                                    const uint16_t* __restrict__ x3,
                                                    const uint16_t* __restrict__ Wlb, const float* __restrict__ bl,
                                                    float* __restrict__ out) {
  __shared__ uint16_t ldsA[64 * 16 * 8];   // 16KB
  __shared__ uint16_t ldsW[64 * 16 * 8];   // 16KB
  int t = threadIdx.x;
  int lane = t & 63, wave = t >> 6;
  int n0 = blockIdx.x * 64;
  int l15 = lane & 15, quad = lane >> 4;

  f32x4 acc[3];
  #pragma unroll
  for (int i = 0; i < 3; ++i) acc[i] = (f32x4){0.f, 0.f, 0.f, 0.f};

  #pragma unroll
  for (int rr = 0; rr < 3; ++rr) {
    const uint16_t* xs = (rr == 0) ? x1 : (rr == 1) ? x2 : x3;
    #pragma unroll
    for (int q = 0; q < 4; ++q) {
      int u = t + q * 256;                 // 0..1023: row = u>>4, swizzled chunk cp = u&15
      int row = u >> 4, cp = u & 15;
      int c = cp ^ (row & 15);             // source chunk (pre-swizzled source, linear LDS dest)
      int rowA = n0 + row; if (rowA >= NN) rowA = NN - 1;
      __builtin_amdgcn_global_load_lds(AS1(xs + (size_t)rowA*HID + c*8), AS3(&ldsA[u * 8]), 16, 0, 0);
      int rowW = row < 48 ? row : 47;
      __builtin_amdgcn_global_load_lds(AS1(Wlb + (size_t)rowW*384 + rr*128 + c*8), AS3(&ldsW[u * 8]), 16, 0, 0);
    }
    __syncthreads();
    #pragma unroll
    for (int kt = 0; kt < 4; ++kt) {
      int cA = kt * 4 + quad;              // chunk index within the 128-col slice
      int rA = wave * 16 + l15;
      bf16x8 af = *(const bf16x8*)&ldsA[(rA * 16 + (cA ^ (rA & 15))) * 8];
      #pragma unroll
      for (int nt = 0; nt < 3; ++nt) {
        int rW = nt * 16 + l15;
        bf16x8 wf = *(const bf16x8*)&ldsW[(rW * 16 + (cA ^ (rW & 15))) * 8];
        acc[nt] = __builtin_amdgcn_mfma_f32_16x16x32_bf16(af, wf, acc[nt], 0, 0, 0);
      }
    }
    __syncthreads();
  }

  int nb = n0 + wave * 16;
  float bias[3]; bool valid[3];
  #pragma unroll
  for (int nt = 0; nt < 3; ++nt) {
    int c = nt*16 + l15;
    valid[nt] = (c < CLS);
    bias[nt] = valid[nt] ? bl[c] : 0.f;
  }

  #pragma unroll
  for (int i = 0; i < 4; ++i) {
    int r = nb + quad*4 + i;
    float v0 = acc[0][i] + bias[0];
    float v1 = acc[1][i] + bias[1];
    float v2 = valid[2] ? (acc[2][i] + bias[2]) : -INFINITY;
    float m = fmaxf(v0, fmaxf(v1, v2));
    #pragma unroll
    for (int off = 8; off >= 1; off >>= 1) m = fmaxf(m, __shfl_xor(m, off, 64));
    float s = __expf(v0 - m) + __expf(v1 - m) + (valid[2] ? __expf(v2 - m) : 0.f);
    #pragma unroll
    for (int off = 8; off >= 1; off >>= 1) s += __shfl_xor(s, off, 64);
    float lse = m + __logf(s);
    if (r < NN) {
      out[(size_t)r*CLS + l15]      = v0 - lse;
      out[(size_t)r*CLS + 16 + l15] = v1 - lse;
      if (valid[2]) out[(size_t)r*CLS + 32 + l15] = v2 - lse;
    }
  }
}

extern "C" void kernel_launch(void* const* d_in, const int* in_sizes, int n_in,
                              void* d_out, int out_size, void* d_ws, size_t ws_size,
                              hipStream_t stream) {
  (void)in_sizes; (void)n_in; (void)out_size; (void)ws_size;
  const float* x0  = (const float*)d_in[0];
  const int*   ei  = (const int*)d_in[1];
  const float* ew  = (const float*)d_in[2];
  const float* W1r = (const float*)d_in[3];
  const float* W1o = (const float*)d_in[4];
  const float* b1  = (const float*)d_in[5];
  const float* W2r = (const float*)d_in[6];
  const float* W2o = (const float*)d_in[7];
  const float* b2  = (const float*)d_in[8];
  const float* W3r = (const float*)d_in[9];
  const float* W3o = (const float*)d_in[10];
  const float* b3  = (const float*)d_in[11];
  const float* Wl  = (const float*)d_in[12];
  const float* bl  = (const float*)d_in[13];
  const int* src = ei;
  const int* dst = ei + NE;

  char* ws = (char*)d_ws;
  size_t off = 0;
  auto alloc = [&](size_t bytes) -> void* {
    void* p = ws + off;
    off += (bytes + 255) & ~(size_t)255;
    return p;
  };
  uint16_t* x0p = (uint16_t*)alloc((size_t)NN * HID * 2);   // also reused as xb2
  uint16_t* xb1 = (uint16_t*)alloc((size_t)NN * HID * 2);
  uint16_t* xb3 = (uint16_t*)alloc((size_t)NN * HID * 2);
  int2*   erec      = (int2*)alloc((size_t)NBUK * BCAP * 8);
  int2*   ebin      = (int2*)alloc((size_t)NBUK * BCAP * 8); // dead after bucket_csr -> reused as xb1f8
  int2*   row_desc  = (int2*)alloc((size_t)NN * 8);
  int*    bfill     = (int*)alloc(NBUK * 4);
  uint16_t* B1 = (uint16_t*)alloc(128 * 256 * 2);
  uint16_t* B2 = (uint16_t*)alloc(128 * 256 * 2);
  uint16_t* B3 = (uint16_t*)alloc(128 * 256 * 2);
  uint16_t* Wlb = (uint16_t*)alloc(48 * 384 * 2);
  uint8_t* x0f8  = (uint8_t*)alloc((size_t)NN * 128);
  uint8_t* xb2f8 = (uint8_t*)alloc((size_t)NN * 128);
  uint16_t* xb2 = x0p;                 // alias: x0p dead after layer-1 fused kernel
  uint8_t* xb1f8 = (uint8_t*)ebin;     // alias: ebin dead after bucket_csr (NBUK*BCAP*8 >= NN*128)

  const int TB = (NE + 8191) / 8192;      // 196 tiles

  binit<<<2, 256, 0, stream>>>(bfill);
  pack_weights<<<384, 256, 0, stream>>>(W1r, W1o, W2r, W2o, W3r, W3o, B1, B2, B3);
  pack_wl<<<72, 256, 0, stream>>>(Wl, Wlb);
  pad_x0<<<NN / 4, 256, 0, stream>>>(x0, x0p, x0f8);
  binscat<<<TB, 512, 0, stream>>>(src, dst, ew, bfill, ebin);
  bucket_csr<<<NBUK, 256, 0, stream>>>(ebin, bfill, row_desc, erec);

  spmm_gemm_kernel<<<(NN + 63) / 64, 256, 0, stream>>>(x0f8, row_desc, erec, x0p, B1, b1, xb1, xb1f8);
  spmm_gemm_kernel<<<(NN + 63) / 64, 256, 0, stream>>>(xb1f8, row_desc, erec, xb1, B2, b2, xb2, xb2f8);
  spmm_gemm_kernel<<<(NN + 63) / 64, 256, 0, stream>>>(xb2f8, row_desc, erec, xb2, B3, b3, xb3, nullptr);

  final_kernel<<<(NN + 63) / 64, 256, 0, stream>>>(xb1, xb2, xb3, Wlb, bl, (float*)d_out);
}

// Round 15
// 381.411 us; speedup vs baseline: 1.1396x; 1.1396x over previous
//
#include <hip/hip_runtime.h>
#include <hip/hip_bf16.h>
#include <stdint.h>

#define NN 100000
#define NE 1600000
#define FIN 100
#define HID 128
#define CLS 47
#define NBUK 391            // ceil(NN/256) buckets of 256 nodes
#define BCAP 4992           // fixed bucket capacity: mean 4096 + 8 sigma + even-pad (<=256) + 16

typedef __attribute__((ext_vector_type(8))) short bf16x8;
typedef __attribute__((ext_vector_type(4))) float f32x4;
typedef __attribute__((ext_vector_type(2))) float f32x2;

#define AS1(p) ((const __attribute__((address_space(1))) void*)(p))
#define AS3(p) ((__attribute__((address_space(3))) void*)(p))

__device__ __forceinline__ uint16_t f2bf(float f) {
  union { float f; uint32_t u; } v; v.f = f;
  uint32_t r = v.u + 0x7fffu + ((v.u >> 16) & 1u);
  return (uint16_t)(r >> 16);
}

// ---- weight packing: B_l[j][k] (128 x 256) bf16; k<128 -> W_rel, k>=128 -> W_root (layer1 zero-padded)
__global__ void pack_weights(const float* __restrict__ W1r, const float* __restrict__ W1o,
                             const float* __restrict__ W2r, const float* __restrict__ W2o,
                             const float* __restrict__ W3r, const float* __restrict__ W3o,
                             uint16_t* __restrict__ B1, uint16_t* __restrict__ B2, uint16_t* __restrict__ B3) {
  int idx = blockIdx.x * 256 + threadIdx.x;      // < 3*128*256
  int l = idx >> 15;
  int rem = idx & 32767;
  int j = rem >> 8;
  int k = rem & 255;
  if (l == 0) {
    uint16_t v = 0;
    if (k < FIN) v = f2bf(W1r[j*FIN + k]);
    else if (k >= 128 && k < 128 + FIN) v = f2bf(W1o[j*FIN + (k - 128)]);
    B1[j*256 + k] = v;
  } else if (l == 1) {
    B2[j*256 + k] = (k < 128) ? f2bf(W2r[j*128 + k]) : f2bf(W2o[j*128 + (k - 128)]);
  } else {
    B3[j*256 + k] = (k < 128) ? f2bf(W3r[j*128 + k]) : f2bf(W3o[j*128 + (k - 128)]);
  }
}

// ---- W_lin [47,384] f32 -> Wlb [48,384] bf16 (row 47 zero)
__global__ void pack_wl(const float* __restrict__ Wl, uint16_t* __restrict__ Wlb) {
  int idx = blockIdx.x * 256 + threadIdx.x;      // < 48*384
  int r = idx / 384;
  int c = idx - r * 384;
  Wlb[idx] = (r < CLS) ? f2bf(Wl[r*384 + c]) : (uint16_t)0;
}

// ---- pad+convert x0 [N,100] f32 -> x0p [N,128] bf16 AND x0f8 [N,128] fp8 (zeros past col 99)
__global__ __launch_bounds__(256) void pad_x0(const float* __restrict__ x0, uint16_t* __restrict__ x0p,
                                              uint8_t* __restrict__ x0f8) {
  int n = blockIdx.x * 4 + (threadIdx.x >> 6);
  int c = 2 * (threadIdx.x & 63);
  uint32_t o = 0;
  uint16_t o8 = 0;
  if (c < FIN) {
    float2 v = *(const float2*)(x0 + (size_t)n*FIN + c);
    o = ((uint32_t)f2bf(v.y) << 16) | (uint32_t)f2bf(v.x);
    o8 = (uint16_t)__builtin_amdgcn_cvt_pk_fp8_f32(v.x, v.y, 0, false);
  }
  *(uint32_t*)(x0p + (size_t)n*HID + c) = o;
  *(uint16_t*)(x0f8 + (size_t)n*128 + c) = o8;
}

// ======== binned CSR build (fixed-capacity buckets) ========
// Stage 0: bfill[b] = b*BCAP
__global__ void binit(int* __restrict__ bfill) {
  int i = blockIdx.x * 256 + threadIdx.x;
  if (i < NBUK) bfill[i] = i * BCAP;
}

// Stage 1: binned scatter. Each block claims contiguous per-bucket chunks so all
// writes to a chunk come from ONE CU -> L2 write-combining -> full-line writebacks.
// Packed rec: x = src | dstLocal<<17 (src<2^17, dstLocal<256), y = weight bits.
__global__ __launch_bounds__(512) void binscat(const int* __restrict__ src, const int* __restrict__ dst,
                                               const float* __restrict__ ew,
                                               int* __restrict__ bfill, int2* __restrict__ ebin) {
  __shared__ int h[NBUK];
  __shared__ int base[NBUK];
  int tid = threadIdx.x;
  for (int i = tid; i < NBUK; i += 512) h[i] = 0;
  __syncthreads();
  int tile0 = blockIdx.x * 8192;
  int n = NE - tile0; if (n > 8192) n = 8192;
  for (int i = tid; i < n; i += 512) atomicAdd(&h[dst[tile0 + i] >> 8], 1);
  __syncthreads();
  for (int i = tid; i < NBUK; i += 512) base[i] = h[i] ? atomicAdd(&bfill[i], h[i]) : 0;
  __syncthreads();
  for (int i = tid; i < NBUK; i += 512) h[i] = 0;
  __syncthreads();
  for (int i = tid; i < n; i += 512) {
    int e = tile0 + i;
    int d = dst[e];
    int b = d >> 8;
    int r = atomicAdd(&h[b], 1);
    ebin[base[b] + r] = make_int2(src[e] | ((d & 255) << 17), __float_as_int(ew[e]));
  }
}

// Stage 2: one block per bucket. LDS hist+scan (even-rounded per-node counts so
// every row stream starts 16B-aligned for int4 erec loads) -> row_desc{start,deg},
// then scatter erec {src byte-offset, weight}. Odd-degree gap slots and 16
// bucket-end slots are zeroed so overrunning tail reads see valid offsets.
__global__ __launch_bounds__(256) void bucket_csr(const int2* __restrict__ ebin,
                                                  const int* __restrict__ bfill,
                                                  int2* __restrict__ row_desc,
                                                  int2* __restrict__ erec) {
  __shared__ int sh[256];
  __shared__ int fill[256];
  __shared__ int cnt2s;
  int b = blockIdx.x;
  int tid = threadIdx.x;
  int base = b * BCAP;
  int cnt = bfill[b] - base;
  sh[tid] = 0;
  __syncthreads();
  for (int i = tid; i < cnt; i += 256) atomicAdd(&sh[(uint32_t)ebin[base + i].x >> 17], 1);
  __syncthreads();
  int histv = sh[tid];
  int hist2 = (histv + 1) & ~1;            // even-rounded
  __syncthreads();
  sh[tid] = hist2;
  __syncthreads();
  for (int off = 1; off < 256; off <<= 1) {
    int tv = (tid >= off) ? sh[tid - off] : 0;
    __syncthreads();
    sh[tid] += tv;
    __syncthreads();
  }
  int excl2 = sh[tid] - hist2;             // even
  if (tid == 255) cnt2s = sh[255];
  int node = b * 256 + tid;
  if (node < NN) row_desc[node] = make_int2(base + excl2, histv);
  fill[tid] = base + excl2;
  if (histv & 1) erec[base + excl2 + histv] = make_int2(0, 0);  // gap slot
  __syncthreads();
  for (int i = tid; i < cnt; i += 256) {
    int2 rec = ebin[base + i];
    int dl = (uint32_t)rec.x >> 17;
    int s = rec.x & 0x1FFFF;
    int pos = atomicAdd(&fill[dl], 1);
    erec[pos] = make_int2(s << 7, rec.y);           // s*128 = byte offset into fp8 row
  }
  if (tid < 16) {
    int p = cnt2s + tid;
    if (p < BCAP) erec[base + p] = make_int2(0, 0);
  }
}

// ---- SpMM: agg[n,:] = sum_{e in row n} w_e * x8[src_e,:]  (x8 = fp8 e4m3 rows, 128B = 1 line)
// Two nodes per wave (half owns its row+stream); lane covers 4 cols (4B).
// erec read as int4 (2 records/load, 16B-aligned starts); batches of 16 + tail.
__global__ __launch_bounds__(256) void spmm_kernel(const uint8_t* __restrict__ x8,
                                                   const int2* __restrict__ row_desc,
                                                   const int2* __restrict__ erec,
                                                   uint16_t* __restrict__ agg) {
  int wave = threadIdx.x >> 6;
  int l = threadIdx.x & 63;
  int half = l >> 5, li = l & 31;
  int n = blockIdx.x * 8 + wave * 2 + half;
  int2 rd = row_desc[n];
  int s0 = rd.x, deg = rd.y;
  const char* xb = (const char*)x8;
  int loff = 4 * li;
  f32x2 a01 = (f32x2){0.f, 0.f}, a23 = (f32x2){0.f, 0.f};
  const int4* ep4 = (const int4*)(erec + s0);      // s0 even -> 16B aligned
  int nfull = deg & ~15;
  const int4* epf = ep4 + (nfull >> 1);
  for (; ep4 < epf; ep4 += 8) {
    int4 r[8];
    #pragma unroll
    for (int u = 0; u < 8; ++u) r[u] = ep4[u];     // imm-offset loads off one base
    uint32_t g[16];
    #pragma unroll
    for (int u = 0; u < 8; ++u) {
      g[2*u]   = *(const uint32_t*)(xb + (size_t)(uint32_t)(r[u].x + loff));
      g[2*u+1] = *(const uint32_t*)(xb + (size_t)(uint32_t)(r[u].z + loff));
    }
    __builtin_amdgcn_sched_barrier(0);             // keep gathers issued before compute
    #pragma unroll
    for (int u = 0; u < 8; ++u) {
      float w0 = __int_as_float(r[u].y);
      float w1 = __int_as_float(r[u].w);
      f32x2 w20 = (f32x2){w0, w0}, w21 = (f32x2){w1, w1};
      a01 += w20 * __builtin_amdgcn_cvt_pk_f32_fp8(g[2*u], false);
      a23 += w20 * __builtin_amdgcn_cvt_pk_f32_fp8(g[2*u], true);
      a01 += w21 * __builtin_amdgcn_cvt_pk_f32_fp8(g[2*u+1], false);
      a23 += w21 * __builtin_amdgcn_cvt_pk_f32_fp8(g[2*u+1], true);
    }
  }
  int rem = deg - nfull;
  if (rem) {                                       // tail: overrun records valid-or-zero; weights masked
    int4 r[8];
    #pragma unroll
    for (int u = 0; u < 8; ++u) r[u] = ep4[u];
    uint32_t g[16];
    #pragma unroll
    for (int u = 0; u < 8; ++u) {
      g[2*u]   = *(const uint32_t*)(xb + (size_t)(uint32_t)(r[u].x + loff));
      g[2*u+1] = *(const uint32_t*)(xb + (size_t)(uint32_t)(r[u].z + loff));
    }
    __builtin_amdgcn_sched_barrier(0);
    #pragma unroll
    for (int u = 0; u < 8; ++u) {
      float w0 = (2*u     < rem) ? __int_as_float(r[u].y) : 0.f;
      float w1 = (2*u + 1 < rem) ? __int_as_float(r[u].w) : 0.f;
      f32x2 w20 = (f32x2){w0, w0}, w21 = (f32x2){w1, w1};
      a01 += w20 * __builtin_amdgcn_cvt_pk_f32_fp8(g[2*u], false);
      a23 += w20 * __builtin_amdgcn_cvt_pk_f32_fp8(g[2*u], true);
      a01 += w21 * __builtin_amdgcn_cvt_pk_f32_fp8(g[2*u+1], false);
      a23 += w21 * __builtin_amdgcn_cvt_pk_f32_fp8(g[2*u+1], true);
    }
  }
  uint2 o;
  o.x = ((uint32_t)f2bf(a01[1]) << 16) | (uint32_t)f2bf(a01[0]);
  o.y = ((uint32_t)f2bf(a23[1]) << 16) | (uint32_t)f2bf(a23[0]);
  *(uint2*)(agg + (size_t)n*HID + 4*li) = o;
}

// ---- fused GEMM: out = relu([A1|A2] @ B^T + bias)
// 64-row tile (grid 1563 -> 6.1 blocks/CU for latency hiding), R1 staging geometry
// (4 lanes x 16B per 64B row window — proven coalescing), LDS chunk-rotation
// swizzle on A and B: dest 16B-chunk qd holds source chunk (qd + (r>>1))&3 ->
// reader fetches (quad - (r>>1))&3; 2-way bank access (free) vs old 8-way.
__global__ __launch_bounds__(256) void gemm_kernel(const uint16_t* __restrict__ A1, const uint16_t* __restrict__ A2,
                                                   const uint16_t* __restrict__ Bm, const float* __restrict__ bias,
                                                   uint16_t* __restrict__ out, uint8_t* __restrict__ out8) {
  __shared__ uint16_t ldsA[64 * 32];    // 4KB
  __shared__ uint16_t ldsB[128 * 32];   // 8KB
  int t = threadIdx.x;
  int n0 = blockIdx.x * 64;
  int lane = t & 63, wave = t >> 6;
  int wm = (wave >> 1) * 32;            // 0 or 32
  int wn = (wave & 1) * 64;             // 0 or 64
  int l15 = lane & 15, quad = lane >> 4;

  f32x4 acc[2][4];
  #pragma unroll
  for (int i = 0; i < 2; ++i)
    #pragma unroll
    for (int j = 0; j < 4; ++j) acc[i][j] = (f32x4){0.f, 0.f, 0.f, 0.f};

  // staging indices (constant across kt)
  int ra = t >> 2, qa = t & 3;                       // A: row 0..63, dest chunk
  int qsA = (qa + (ra >> 1)) & 3;                    // source chunk (rotation)
  int rowA = n0 + ra; if (rowA >= NN) rowA = NN - 1;

  for (int kt = 0; kt < 8; ++kt) {
    int kbase = kt * 32;
    const uint16_t* Asrc = (kbase < 128) ? A1 : A2;
    int klocal = kbase & 127;
    __builtin_amdgcn_global_load_lds(AS1(Asrc + (size_t)rowA*HID + klocal + qsA*8), AS3(&ldsA[t * 8]), 16, 0, 0);
    #pragma unroll
    for (int p = 0; p < 2; ++p) {
      int u = t + p * 256;                           // 0..511
      int j = u >> 2, qb = u & 3;
      int qsB = (qb + (j >> 1)) & 3;
      __builtin_amdgcn_global_load_lds(AS1(Bm + j*256 + kbase + qsB*8), AS3(&ldsB[u * 8]), 16, 0, 0);
    }
    __syncthreads();
    bf16x8 af[2], bfr[4];
    #pragma unroll
    for (int mi = 0; mi < 2; ++mi) {
      int rA = wm + mi*16 + l15;
      af[mi] = *(const bf16x8*)&ldsA[rA * 32 + ((quad - (rA >> 1)) & 3) * 8];
    }
    #pragma unroll
    for (int ni = 0; ni < 4; ++ni) {
      int j = wn + ni*16 + l15;
      bfr[ni] = *(const bf16x8*)&ldsB[j * 32 + ((quad - (j >> 1)) & 3) * 8];
    }
    #pragma unroll
    for (int mi = 0; mi < 2; ++mi)
      #pragma unroll
      for (int ni = 0; ni < 4; ++ni)
        acc[mi][ni] = __builtin_amdgcn_mfma_f32_16x16x32_bf16(af[mi], bfr[ni], acc[mi][ni], 0, 0, 0);
    __syncthreads();
  }

  #pragma unroll
  for (int mi = 0; mi < 2; ++mi) {
    #pragma unroll
    for (int ni = 0; ni < 4; ++ni) {
      int c = wn + ni*16 + l15;
      float bc = bias[c];
      #pragma unroll
      for (int i = 0; i < 4; ++i) {
        int r = n0 + wm + mi*16 + quad*4 + i;
        if (r < NN) {
          float v = acc[mi][ni][i] + bc;
          v = v > 0.f ? v : 0.f;
          out[(size_t)r*HID + c] = f2bf(v);
          if (out8) out8[(size_t)r*128 + c] = (uint8_t)__builtin_amdgcn_cvt_pk_fp8_f32(v, v, 0, false);
        }
      }
    }
  }
}

// ---- final: logits = [x1|x2|x3] @ Wlb^T + bl ; log_softmax ; store f32
// 3 rounds (one per layer input): stage full 64x128 A-slice + 64x128 W-slice with
// row-contiguous global loads into XOR-swizzled LDS [row][c^(row&15)][8];
// conflict-free ds_read_b128 (bank = 4*(c^l15), disjoint). 6 barriers total.
__global__ __launch_bounds__(256) void final_kernel(const uint16_t* __restrict__ x1, const uint16_t* __restrict__ x2,
                                                    const uint16_t* __restrict__ x3,
                                                    const uint16_t* __restrict__ Wlb, const float* __restrict__ bl,
                                                    float* __restrict__ out) {
  __shared__ uint16_t ldsA[64 * 16 * 8];   // 16KB
  __shared__ uint16_t ldsW[64 * 16 * 8];   // 16KB
  int t = threadIdx.x;
  int lane = t & 63, wave = t >> 6;
  int n0 = blockIdx.x * 64;
  int l15 = lane & 15, quad = lane >> 4;

  f32x4 acc[3];
  #pragma unroll
  for (int i = 0; i < 3; ++i) acc[i] = (f32x4){0.f, 0.f, 0.f, 0.f};

  #pragma unroll
  for (int rr = 0; rr < 3; ++rr) {
    const uint16_t* xs = (rr == 0) ? x1 : (rr == 1) ? x2 : x3;
    #pragma unroll
    for (int q = 0; q < 4; ++q) {
      int u = t + q * 256;                 // 0..1023: row = u>>4, swizzled chunk cp = u&15
      int row = u >> 4, cp = u & 15;
      int c = cp ^ (row & 15);             // source chunk (pre-swizzled source, linear LDS dest)
      int rowA = n0 + row; if (rowA >= NN) rowA = NN - 1;
      __builtin_amdgcn_global_load_lds(AS1(xs + (size_t)rowA*HID + c*8), AS3(&ldsA[u * 8]), 16, 0, 0);
      int rowW = row < 48 ? row : 47;
      __builtin_amdgcn_global_load_lds(AS1(Wlb + (size_t)rowW*384 + rr*128 + c*8), AS3(&ldsW[u * 8]), 16, 0, 0);
    }
    __syncthreads();
    #pragma unroll
    for (int kt = 0; kt < 4; ++kt) {
      int cA = kt * 4 + quad;              // chunk index within the 128-col slice
      int rA = wave * 16 + l15;
      bf16x8 af = *(const bf16x8*)&ldsA[(rA * 16 + (cA ^ (rA & 15))) * 8];
      #pragma unroll
      for (int nt = 0; nt < 3; ++nt) {
        int rW = nt * 16 + l15;
        bf16x8 wf = *(const bf16x8*)&ldsW[(rW * 16 + (cA ^ (rW & 15))) * 8];
        acc[nt] = __builtin_amdgcn_mfma_f32_16x16x32_bf16(af, wf, acc[nt], 0, 0, 0);
      }
    }
    __syncthreads();
  }

  int nb = n0 + wave * 16;
  float bias[3]; bool valid[3];
  #pragma unroll
  for (int nt = 0; nt < 3; ++nt) {
    int c = nt*16 + l15;
    valid[nt] = (c < CLS);
    bias[nt] = valid[nt] ? bl[c] : 0.f;
  }

  #pragma unroll
  for (int i = 0; i < 4; ++i) {
    int r = nb + quad*4 + i;
    float v0 = acc[0][i] + bias[0];
    float v1 = acc[1][i] + bias[1];
    float v2 = valid[2] ? (acc[2][i] + bias[2]) : -INFINITY;
    float m = fmaxf(v0, fmaxf(v1, v2));
    #pragma unroll
    for (int off = 8; off >= 1; off >>= 1) m = fmaxf(m, __shfl_xor(m, off, 64));
    float s = __expf(v0 - m) + __expf(v1 - m) + (valid[2] ? __expf(v2 - m) : 0.f);
    #pragma unroll
    for (int off = 8; off >= 1; off >>= 1) s += __shfl_xor(s, off, 64);
    float lse = m + __logf(s);
    if (r < NN) {
      out[(size_t)r*CLS + l15]      = v0 - lse;
      out[(size_t)r*CLS + 16 + l15] = v1 - lse;
      if (valid[2]) out[(size_t)r*CLS + 32 + l15] = v2 - lse;
    }
  }
}

extern "C" void kernel_launch(void* const* d_in, const int* in_sizes, int n_in,
                              void* d_out, int out_size, void* d_ws, size_t ws_size,
                              hipStream_t stream) {
  (void)in_sizes; (void)n_in; (void)out_size; (void)ws_size;
  const float* x0  = (const float*)d_in[0];
  const int*   ei  = (const int*)d_in[1];
  const float* ew  = (const float*)d_in[2];
  const float* W1r = (const float*)d_in[3];
  const float* W1o = (const float*)d_in[4];
  const float* b1  = (const float*)d_in[5];
  const float* W2r = (const float*)d_in[6];
  const float* W2o = (const float*)d_in[7];
  const float* b2  = (const float*)d_in[8];
  const float* W3r = (const float*)d_in[9];
  const float* W3o = (const float*)d_in[10];
  const float* b3  = (const float*)d_in[11];
  const float* Wl  = (const float*)d_in[12];
  const float* bl  = (const float*)d_in[13];
  const int* src = ei;
  const int* dst = ei + NE;

  char* ws = (char*)d_ws;
  size_t off = 0;
  auto alloc = [&](size_t bytes) -> void* {
    void* p = ws + off;
    off += (bytes + 255) & ~(size_t)255;
    return p;
  };
  uint16_t* x0p = (uint16_t*)alloc((size_t)NN * HID * 2);   // also reused as xb2
  uint16_t* xb1 = (uint16_t*)alloc((size_t)NN * HID * 2);
  uint16_t* xb3 = (uint16_t*)alloc((size_t)NN * HID * 2);
  uint16_t* agg = (uint16_t*)alloc((size_t)NN * HID * 2);
  int2*   erec      = (int2*)alloc((size_t)NBUK * BCAP * 8);
  int2*   ebin      = (int2*)alloc((size_t)NBUK * BCAP * 8); // dead after bucket_csr -> reused as xb1f8
  int2*   row_desc  = (int2*)alloc((size_t)NN * 8);
  int*    bfill     = (int*)alloc(NBUK * 4);
  uint16_t* B1 = (uint16_t*)alloc(128 * 256 * 2);
  uint16_t* B2 = (uint16_t*)alloc(128 * 256 * 2);
  uint16_t* B3 = (uint16_t*)alloc(128 * 256 * 2);
  uint16_t* Wlb = (uint16_t*)alloc(48 * 384 * 2);
  uint8_t* x0f8  = (uint8_t*)alloc((size_t)NN * 128);
  uint8_t* xb2f8 = (uint8_t*)alloc((size_t)NN * 128);
  uint16_t* xb2 = x0p;                 // alias: x0p dead after layer-1 GEMM
  uint8_t* xb1f8 = (uint8_t*)ebin;     // alias: ebin dead after bucket_csr (NBUK*BCAP*8 >= NN*128)

  const int TB = (NE + 8191) / 8192;      // 196 tiles

  binit<<<2, 256, 0, stream>>>(bfill);
  pack_weights<<<384, 256, 0, stream>>>(W1r, W1o, W2r, W2o, W3r, W3o, B1, B2, B3);
  pack_wl<<<72, 256, 0, stream>>>(Wl, Wlb);
  pad_x0<<<NN / 4, 256, 0, stream>>>(x0, x0p, x0f8);
  binscat<<<TB, 512, 0, stream>>>(src, dst, ew, bfill, ebin);
  bucket_csr<<<NBUK, 256, 0, stream>>>(ebin, bfill, row_desc, erec);

  spmm_kernel<<<NN / 8, 256, 0, stream>>>(x0f8, row_desc, erec, agg);
  gemm_kernel<<<(NN + 63) / 64, 256, 0, stream>>>(agg, x0p, B1, b1, xb1, xb1f8);
  spmm_kernel<<<NN / 8, 256, 0, stream>>>(xb1f8, row_desc, erec, agg);
  gemm_kernel<<<(NN + 63) / 64, 256, 0, stream>>>(agg, xb1, B2, b2, xb2, xb2f8);
  spmm_kernel<<<NN / 8, 256, 0, stream>>>(xb2f8, row_desc, erec, agg);
  gemm_kernel<<<(NN + 63) / 64, 256, 0, stream>>>(agg, xb2, B3, b3, xb3, nullptr);

  final_kernel<<<(NN + 63) / 64, 256, 0, stream>>>(xb1, xb2, xb3, Wlb, bl, (float*)d_out);
}